// Round 2
// baseline (2384.228 us; speedup 1.0000x reference)
//
#include <hip/hip_runtime.h>
#include <stdint.h>

// Problem constants (B=256, L=2048, H=64, TE=64)
#define NB 256
#define NL 2048
#define NM (NB*NL)   // 524288 positions

// ---------- bf16 helpers (manual, RNE) ----------
static __device__ __forceinline__ unsigned short f2bf(float f) {
    union { float f; uint32_t u; } v; v.f = f;
    uint32_t u = v.u;
    uint32_t r = u + 0x7fffu + ((u >> 16) & 1u);
    return (unsigned short)(r >> 16);
}
static __device__ __forceinline__ float bflo(uint32_t u) {
    union { uint32_t u; float f; } v; v.u = u << 16; return v.f;
}
static __device__ __forceinline__ float bfhi(uint32_t u) {
    union { uint32_t u; float f; } v; v.u = u & 0xffff0000u; return v.f;
}

// ---------- per-direction proj + gates (weights wave-uniform -> s_loads) ----------
static __device__ __forceinline__ void do_dir(
    const float* __restrict__ pw, const float* __restrict__ pb,   // proj [64,67],[64]
    const float* __restrict__ wz, const float* __restrict__ bz,   // [64,64],[64]
    const float* __restrict__ wh, const float* __restrict__ bh,
    const float (&tenc)[64], float x0, float x1, float mc,
    uint32_t* __restrict__ dst /* + o*NL strided */)
{
    float inp[64];
#pragma unroll
    for (int o = 0; o < 64; ++o) {
        float acc = pb[o];
        acc = fmaf(x0, pw[o*67+0], acc);
        acc = fmaf(x1, pw[o*67+1], acc);
        acc = fmaf(mc, pw[o*67+2], acc);
#pragma unroll
        for (int k = 0; k < 64; ++k) acc = fmaf(tenc[k], pw[o*67+3+k], acc);
        inp[o] = acc;
    }
#pragma unroll 1
    for (int o = 0; o < 64; ++o) {
        float az = bz[o], ah = bh[o];
#pragma unroll
        for (int k = 0; k < 64; ++k) {
            az = fmaf(inp[k], wz[o*64+k], az);
            ah = fmaf(inp[k], wh[o*64+k], ah);
        }
        float z  = 1.f / (1.f + __expf(-az));
        float c  = fminf(fmaxf(ah, -15.f), 15.f);
        float e  = __expf(2.f * c);
        float th = (e - 1.f) / (e + 1.f);
        float av = 1.f - z;
        float bv = z * th;
        dst[(size_t)o * NL] = ((uint32_t)f2bf(bv) << 16) | (uint32_t)f2bf(av);
    }
}

// ---------- kernel 1: time-MLP + proj + gates -> packed (a,b) bf16, [b_local][h][l] ----------
__global__ __launch_bounds__(256) void prep_kernel(
    const float* __restrict__ x, const float* __restrict__ t,
    const float* __restrict__ mtok,
    const float* __restrict__ te_w1, const float* __restrict__ te_b1,
    const float* __restrict__ te_w2, const float* __restrict__ te_b2,
    const float* __restrict__ fpw, const float* __restrict__ fpb,
    const float* __restrict__ bpw, const float* __restrict__ bpb,
    const float* __restrict__ fwz, const float* __restrict__ fbz,
    const float* __restrict__ fwh, const float* __restrict__ fbh,
    const float* __restrict__ bwz, const float* __restrict__ bbz,
    const float* __restrict__ bwh, const float* __restrict__ bbh,
    int b0,                                  // first batch row of this group
    unsigned short* __restrict__ tenc_out,   // [Bg*L,64] bf16 (group-local)
    uint32_t* __restrict__ abf,              // [Bg*64, L] packed (a lo, b hi)
    uint32_t* __restrict__ abb)
{
    const int posl = blockIdx.x * 256 + threadIdx.x;  // group-local position
    const int bl   = posl >> 11;                      // group-local batch row
    const int ll   = posl & 2047;
    const int gpos = (b0 << 11) + posl;               // global position

    const float tv = t[gpos];
    float te1[64];
#pragma unroll
    for (int k = 0; k < 64; ++k)
        te1[k] = fmaxf(fmaf(tv, te_w1[k], te_b1[k]), 0.f);

    float tenc[64];
#pragma unroll
    for (int o = 0; o < 64; ++o) {
        float acc = te_b2[o];
#pragma unroll
        for (int k = 0; k < 64; ++k) acc = fmaf(te1[k], te_w2[o*64+k], acc);
        tenc[o] = acc;
        tenc_out[(size_t)posl * 64 + o] = f2bf(acc);
    }

    const float mc = x[(size_t)gpos*3+2];
    const bool masked = (mc == 0.f);
    const float x0 = masked ? mtok[0] : x[(size_t)gpos*3+0];
    const float x1 = masked ? mtok[1] : x[(size_t)gpos*3+1];

    uint32_t* dstf = abf + (size_t)(bl * 64) * NL + ll;
    uint32_t* dstb = abb + (size_t)(bl * 64) * NL + ll;
    do_dir(fpw, fpb, fwz, fbz, fwh, fbh, tenc, x0, x1, mc, dstf);
    do_dir(bpw, bpb, bwz, bbz, bwh, bbh, tenc, x0, x1, mc, dstb);
}

// ---------- kernel 2: 2*Bg*64 independent linear scans ----------
__global__ __launch_bounds__(64) void scan_kernel(
    const uint32_t* __restrict__ abf, const uint32_t* __restrict__ abb,
    int Bg,
    unsigned short* __restrict__ hf, unsigned short* __restrict__ hb) // [b_l][l][h] bf16
{
    const int tid = blockIdx.x * 64 + threadIdx.x;   // 0 .. 2*Bg*64-1
    const int nfw = Bg * 64;
    const int dir = (tid >= nfw) ? 1 : 0;
    const int bh  = tid - dir * nfw;                 // group-local b*64+h
    const int bl  = bh >> 6;
    const int hh  = bh & 63;

    const uint32_t* ab = (dir ? abb : abf) + (size_t)bh * NL;
    unsigned short* out = (dir ? hb : hf) + (size_t)bl * NL * 64 + hh;

    float hv = 0.f;
    if (dir == 0) {
#pragma unroll 1
        for (int l0 = 0; l0 < NL; l0 += 32) {
            const uint4* p = (const uint4*)(ab + l0);
            uint4 v[8];
#pragma unroll
            for (int i = 0; i < 8; ++i) v[i] = p[i];
            uint32_t q[32];
#pragma unroll
            for (int i = 0; i < 8; ++i) {
                q[4*i+0]=v[i].x; q[4*i+1]=v[i].y; q[4*i+2]=v[i].z; q[4*i+3]=v[i].w;
            }
            unsigned short* op = out + (size_t)l0 * 64;
#pragma unroll
            for (int i = 0; i < 32; ++i) {
                *op = f2bf(hv); op += 64;
                hv = fmaf(bflo(q[i]), hv, bfhi(q[i]));   // h = a*h + b
            }
        }
    } else {
#pragma unroll 1
        for (int l0 = NL - 32; l0 >= 0; l0 -= 32) {
            const uint4* p = (const uint4*)(ab + l0);
            uint4 v[8];
#pragma unroll
            for (int i = 0; i < 8; ++i) v[i] = p[i];
            uint32_t q[32];
#pragma unroll
            for (int i = 0; i < 8; ++i) {
                q[4*i+0]=v[i].x; q[4*i+1]=v[i].y; q[4*i+2]=v[i].z; q[4*i+3]=v[i].w;
            }
            unsigned short* op = out + (size_t)(l0 + 31) * 64;
#pragma unroll
            for (int i = 31; i >= 0; --i) {
                *op = f2bf(hv); op -= 64;
                hv = fmaf(bflo(q[i]), hv, bfhi(q[i]));
            }
        }
    }
}

// ---------- kernel 3: head GEMM (192 -> 128 relu -> 1) ----------
__global__ __launch_bounds__(256) void head_kernel(
    const float* __restrict__ x,
    const unsigned short* __restrict__ tenc,
    const unsigned short* __restrict__ hf, const unsigned short* __restrict__ hb,
    const float* __restrict__ w1, const float* __restrict__ b1,  // [128,192],[128]
    const float* __restrict__ w2, const float* __restrict__ b2,  // [1,128],[1]
    int b0,
    float* __restrict__ out)
{
    const int posl = blockIdx.x * 256 + threadIdx.x;
    const int bl   = posl >> 11;
    const int ll   = posl & 2047;
    const int gpos = (b0 << 11) + posl;

    const float mc = x[(size_t)gpos*3+2];
    const bool unm = (mc > 0.f);
    const size_t rowbase = (size_t)bl * NL * 64;
    const uint4* pf = (const uint4*)(hf + rowbase + (size_t)(unm ? ll : (NL-1)) * 64);
    const uint4* pb = (const uint4*)(hb + rowbase + (size_t)(unm ? ll : 0) * 64);
    const uint4* pt = (const uint4*)(tenc + (size_t)posl * 64);

    float abi[192];
#pragma unroll
    for (int i = 0; i < 8; ++i) {
        uint4 q = pf[i];
        abi[i*8+0]=bflo(q.x); abi[i*8+1]=bfhi(q.x);
        abi[i*8+2]=bflo(q.y); abi[i*8+3]=bfhi(q.y);
        abi[i*8+4]=bflo(q.z); abi[i*8+5]=bfhi(q.z);
        abi[i*8+6]=bflo(q.w); abi[i*8+7]=bfhi(q.w);
    }
#pragma unroll
    for (int i = 0; i < 8; ++i) {
        uint4 q = pb[i];
        abi[64+i*8+0]=bflo(q.x); abi[64+i*8+1]=bfhi(q.x);
        abi[64+i*8+2]=bflo(q.y); abi[64+i*8+3]=bfhi(q.y);
        abi[64+i*8+4]=bflo(q.z); abi[64+i*8+5]=bfhi(q.z);
        abi[64+i*8+6]=bflo(q.w); abi[64+i*8+7]=bfhi(q.w);
    }
#pragma unroll
    for (int i = 0; i < 8; ++i) {
        uint4 q = pt[i];
        abi[128+i*8+0]=bflo(q.x); abi[128+i*8+1]=bfhi(q.x);
        abi[128+i*8+2]=bflo(q.y); abi[128+i*8+3]=bfhi(q.y);
        abi[128+i*8+4]=bflo(q.z); abi[128+i*8+5]=bfhi(q.z);
        abi[128+i*8+6]=bflo(q.w); abi[128+i*8+7]=bfhi(q.w);
    }

    float acc2 = b2[0];
#pragma unroll 1
    for (int j = 0; j < 128; j += 4) {
        float a0 = b1[j+0], a1 = b1[j+1], a2 = b1[j+2], a3 = b1[j+3];
#pragma unroll
        for (int k = 0; k < 192; ++k) {
            const float v = abi[k];
            a0 = fmaf(v, w1[(j+0)*192+k], a0);
            a1 = fmaf(v, w1[(j+1)*192+k], a1);
            a2 = fmaf(v, w1[(j+2)*192+k], a2);
            a3 = fmaf(v, w1[(j+3)*192+k], a3);
        }
        acc2 = fmaf(fmaxf(a0, 0.f), w2[j+0], acc2);
        acc2 = fmaf(fmaxf(a1, 0.f), w2[j+1], acc2);
        acc2 = fmaf(fmaxf(a2, 0.f), w2[j+2], acc2);
        acc2 = fmaf(fmaxf(a3, 0.f), w2[j+3], acc2);
    }
    out[gpos] = acc2;
}

extern "C" void kernel_launch(void* const* d_in, const int* in_sizes, int n_in,
                              void* d_out, int out_size, void* d_ws, size_t ws_size,
                              hipStream_t stream)
{
    const float* x     = (const float*)d_in[0];
    const float* t     = (const float*)d_in[1];
    const float* mtok  = (const float*)d_in[2];
    const float* te_w1 = (const float*)d_in[3];
    const float* te_b1 = (const float*)d_in[4];
    const float* te_w2 = (const float*)d_in[5];
    const float* te_b2 = (const float*)d_in[6];
    const float* fpw   = (const float*)d_in[7];
    const float* fpb   = (const float*)d_in[8];
    const float* bpw   = (const float*)d_in[9];
    const float* bpb   = (const float*)d_in[10];
    const float* fwz   = (const float*)d_in[11];
    const float* fbz   = (const float*)d_in[12];
    const float* fwh   = (const float*)d_in[13];
    const float* fbh   = (const float*)d_in[14];
    const float* bwz   = (const float*)d_in[15];
    const float* bbz   = (const float*)d_in[16];
    const float* bwh   = (const float*)d_in[17];
    const float* bbh   = (const float*)d_in[18];
    const float* w1    = (const float*)d_in[19];
    const float* b1    = (const float*)d_in[20];
    const float* w2    = (const float*)d_in[21];
    const float* b2    = (const float*)d_in[22];

    // Per-batch-row workspace footprint (bytes):
    //   abf+abb : 2 * 64*2048*4 = 1,048,576
    //   hf+hb   : 2 * 2048*64*2 =   524,288
    //   tenc    :     2048*64*2 =   262,144
    const size_t per_b = 1835008ull;
    int Bg = NB;
    while ((size_t)Bg * per_b > ws_size && Bg > 1) Bg >>= 1;
    const int nG = NB / Bg;

    char* ws = (char*)d_ws;
    uint32_t*       abf  = (uint32_t*)(ws);
    uint32_t*       abb  = abf + (size_t)Bg * 64 * NL;
    unsigned short* hf   = (unsigned short*)(abb + (size_t)Bg * 64 * NL);
    unsigned short* hb   = hf + (size_t)Bg * NL * 64;
    unsigned short* tenc = hb + (size_t)Bg * NL * 64;

    for (int g = 0; g < nG; ++g) {
        const int b0 = g * Bg;
        const int posBlocks = (Bg * NL) / 256;

        prep_kernel<<<posBlocks, 256, 0, stream>>>(
            x, t, mtok, te_w1, te_b1, te_w2, te_b2,
            fpw, fpb, bpw, bpb, fwz, fbz, fwh, fbh, bwz, bbz, bwh, bbh,
            b0, tenc, abf, abb);

        scan_kernel<<<2 * Bg, 64, 0, stream>>>(abf, abb, Bg, hf, hb);

        head_kernel<<<posBlocks, 256, 0, stream>>>(
            x, tenc, hf, hb, w1, b1, w2, b2, b0, (float*)d_out);
    }
}